// Round 2
// baseline (199.268 us; speedup 1.0000x reference)
//
#include <hip/hip_runtime.h>
#include <hip/hip_cooperative_groups.h>
#include <math.h>

namespace cg = cooperative_groups;

#define NROWS   96
#define DIM     768
#define THRESH  0.3f
#define NPAIR   4560            // 96*95/2
#define PTOT    9120            // 2*NPAIR
#define QTOT    9216            // 96*96
#define NDOT    18336           // 2*NPAIR + QTOT
#define SEG     576             // QTOT / 16
#define NSEG    16
#define NBLK    576             // = 36 pos-groups x 16 segments (phase-2 grid)
#define NWAVES  (NBLK * 4)

// ws layout: pos[9120] f32 | neg[9216] f32 | acc (double, 8B-aligned at 73344)

__global__ __launch_bounds__(256, 4) void fused_kernel(
    const float* __restrict__ stereos, const float* __restrict__ astereos,
    float* __restrict__ pos, float* __restrict__ neg,
    double* __restrict__ acc, float* __restrict__ out)
{
    cg::grid_group grid = cg::this_grid();
    __shared__ __align__(16) float lneg[SEG];
    __shared__ float red[4];
    int tid  = threadIdx.x;
    int wave = tid >> 6, lane = tid & 63;

    if (blockIdx.x == 0 && tid == 0) *acc = 0.0;   // ws is poisoned every call

    // ---- phase 1: all sims, norms fused into the dot (3 accumulators) ----
    int gwave = blockIdx.x * 4 + wave;             // 0..2303
    for (int d = gwave; d < NDOT; d += NWAVES) {
        const float *va, *vb;
        float* outp;
        if (d < 2 * NPAIR) {
            int t = d;
            const float* base;
            if (d < NPAIR) { base = stereos; }
            else           { t = d - NPAIR; base = astereos; }
            // triangular decode: B(i) = i*(191-i)/2 <= t < B(i+1)
            int i = (int)((191.0 - sqrt(36481.0 - 8.0 * (double)t)) * 0.5);
            if (i < 0) i = 0;
            if (i > 94) i = 94;
            while (i > 0 && (i * (191 - i)) / 2 > t) --i;
            while (((i + 1) * (190 - i)) / 2 <= t) ++i;
            int j = t - (i * (191 - i)) / 2 + i + 1;
            va = base + i * DIM;
            vb = base + j * DIM;
            outp = pos + d;
        } else {
            int t = d - 2 * NPAIR;
            int i = t / NROWS, j = t - i * NROWS;
            va = astereos + i * DIM;
            vb = stereos + j * DIM;
            outp = neg + t;
        }
        float sab = 0.f, saa = 0.f, sbb = 0.f;
#pragma unroll
        for (int k = 0; k < 3; k++) {              // 192 float4s / 64 lanes
            float4 a = ((const float4*)va)[lane + 64 * k];
            float4 b = ((const float4*)vb)[lane + 64 * k];
            sab += a.x*b.x + a.y*b.y + a.z*b.z + a.w*b.w;
            saa += a.x*a.x + a.y*a.y + a.z*a.z + a.w*a.w;
            sbb += b.x*b.x + b.y*b.y + b.z*b.z + b.w*b.w;
        }
        for (int off = 32; off; off >>= 1) {
            sab += __shfl_down(sab, off);
            saa += __shfl_down(saa, off);
            sbb += __shfl_down(sbb, off);
        }
        if (lane == 0) {
            float inva = 1.0f / fmaxf(sqrtf(saa), 1e-8f);
            float invb = 1.0f / fmaxf(sqrtf(sbb), 1e-8f);
            *outp = sab * inva * invb;
        }
    }

    grid.sync();

    // ---- phase 2: hinge via abs identity ----
    // sum_q max(0, n_q - c) = 0.5*(segSum - SEG*c + sum_q |n_q - c|), c = p - T
    int seg = blockIdx.x & (NSEG - 1);
    int pg  = blockIdx.x >> 4;                     // 0..35
    const float* segp = neg + seg * SEG;
    float lsum = 0.f;
    for (int k = tid; k < SEG; k += 256) {
        float v = segp[k];
        lneg[k] = v;
        lsum += v;
    }
    for (int off = 32; off; off >>= 1) lsum += __shfl_down(lsum, off);
    if (lane == 0) red[wave] = lsum;
    __syncthreads();
    float segSum = red[0] + red[1] + red[2] + red[3];

    int p = pg * 256 + tid;
    float thisSum = 0.f;
    if (p < PTOT) {
        float c = pos[p] - THRESH;
        float aabs = 0.f;
        const float4* l4 = (const float4*)lneg;    // uniform addr -> broadcast
#pragma unroll 4
        for (int k = 0; k < SEG / 4; k++) {
            float4 n = l4[k];
            aabs += fabsf(n.x - c) + fabsf(n.y - c) +
                    fabsf(n.z - c) + fabsf(n.w - c);
        }
        thisSum = 0.5f * (segSum - (float)SEG * c + aabs);
    }
    for (int off = 32; off; off >>= 1) thisSum += __shfl_down(thisSum, off);
    __syncthreads();                                // red[] reuse
    if (lane == 0) red[wave] = thisSum;
    __syncthreads();
    if (tid == 0) atomicAdd(acc, (double)(red[0] + red[1] + red[2] + red[3]));

    grid.sync();

    // ---- phase 3: finalize ----
    if (blockIdx.x == 0 && tid == 0)
        out[0] = (float)(acc[0] / (double)((long long)PTOT * (long long)QTOT));
}

extern "C" void kernel_launch(void* const* d_in, const int* in_sizes, int n_in,
                              void* d_out, int out_size, void* d_ws, size_t ws_size,
                              hipStream_t stream)
{
    const float* stereos  = (const float*)d_in[0];
    const float* astereos = (const float*)d_in[1];

    float*  pos = (float*)d_ws;
    float*  neg = pos + PTOT;
    double* acc = (double*)((char*)d_ws + (size_t)(PTOT + QTOT) * sizeof(float));
    float*  out = (float*)d_out;

    void* args[] = {&stereos, &astereos, &pos, &neg, &acc, &out};
    hipLaunchCooperativeKernel((void*)fused_kernel, dim3(NBLK), dim3(256),
                               args, 0, stream);
}

// Round 3
// 85.063 us; speedup vs baseline: 2.3426x; 2.3426x over previous
//
#include <hip/hip_runtime.h>
#include <math.h>

#define NROWS   96
#define DIM     768
#define THRESH  0.3f
#define NPAIR   4560            // 96*95/2
#define PTOT    9120            // 2*NPAIR
#define QTOT    9216            // 96*96
#define NDOT    18336           // 2*NPAIR + QTOT
#define SEG     576             // QTOT / 16
#define NSEG    16
#define NBLK1   576
#define NWAVES1 (NBLK1 * 4)
#define NBLK2   ((PTOT + 255) / 256 * NSEG)   // 36 * 16 = 576

// ws layout (bytes): pos[9120]f32 @0 | neg[9216]f32 @36480 | acc f64 @73344 |
//                    counter u32 @73352

// ---- K1: all sims, norms fused into the dot; also zero acc & counter -------
__global__ __launch_bounds__(256) void sims_kernel(
    const float* __restrict__ stereos, const float* __restrict__ astereos,
    float* __restrict__ pos, float* __restrict__ neg,
    double* __restrict__ acc, unsigned int* __restrict__ counter)
{
    int tid  = threadIdx.x;
    int wave = tid >> 6, lane = tid & 63;

    if (blockIdx.x == 0 && tid == 0) { *acc = 0.0; *counter = 0u; }

    int gwave = blockIdx.x * 4 + wave;             // 0..2303
    for (int d = gwave; d < NDOT; d += NWAVES1) {
        const float *va, *vb;
        float* outp;
        if (d < 2 * NPAIR) {
            int t = d;
            const float* base;
            if (d < NPAIR) { base = stereos; }
            else           { t = d - NPAIR; base = astereos; }
            // triangular decode: B(i) = i*(191-i)/2 <= t < B(i+1)
            int i = (int)((191.0 - sqrt(36481.0 - 8.0 * (double)t)) * 0.5);
            if (i < 0) i = 0;
            if (i > 94) i = 94;
            while (i > 0 && (i * (191 - i)) / 2 > t) --i;
            while (((i + 1) * (190 - i)) / 2 <= t) ++i;
            int j = t - (i * (191 - i)) / 2 + i + 1;
            va = base + i * DIM;
            vb = base + j * DIM;
            outp = pos + d;
        } else {
            int t = d - 2 * NPAIR;
            int i = t / NROWS, j = t - i * NROWS;
            va = astereos + i * DIM;
            vb = stereos + j * DIM;
            outp = neg + t;
        }
        float sab = 0.f, saa = 0.f, sbb = 0.f;
#pragma unroll
        for (int k = 0; k < 3; k++) {              // 192 float4s / 64 lanes
            float4 a = ((const float4*)va)[lane + 64 * k];
            float4 b = ((const float4*)vb)[lane + 64 * k];
            sab += a.x*b.x + a.y*b.y + a.z*b.z + a.w*b.w;
            saa += a.x*a.x + a.y*a.y + a.z*a.z + a.w*a.w;
            sbb += b.x*b.x + b.y*b.y + b.z*b.z + b.w*b.w;
        }
        for (int off = 32; off; off >>= 1) {
            sab += __shfl_down(sab, off);
            saa += __shfl_down(saa, off);
            sbb += __shfl_down(sbb, off);
        }
        if (lane == 0) {
            float inva = 1.0f / fmaxf(sqrtf(saa), 1e-8f);
            float invb = 1.0f / fmaxf(sqrtf(sbb), 1e-8f);
            *outp = sab * inva * invb;
        }
    }
}

// ---- K2: hinge via abs identity + last-block finalize ----------------------
// sum_q max(0, n_q - c) = 0.5*(segSum - SEG*c + sum_q |n_q - c|), c = p - T
__global__ __launch_bounds__(256) void hinge_kernel(
    const float* __restrict__ pos, const float* __restrict__ neg,
    double* __restrict__ acc, unsigned int* __restrict__ counter,
    float* __restrict__ out)
{
    __shared__ __align__(16) float lneg[SEG];
    __shared__ float red[4];
    int tid  = threadIdx.x;
    int wave = tid >> 6, lane = tid & 63;

    int seg = blockIdx.x & (NSEG - 1);
    int pg  = blockIdx.x >> 4;                     // 0..35
    const float* segp = neg + seg * SEG;
    float lsum = 0.f;
    for (int k = tid; k < SEG; k += 256) {
        float v = segp[k];
        lneg[k] = v;
        lsum += v;
    }
    for (int off = 32; off; off >>= 1) lsum += __shfl_down(lsum, off);
    if (lane == 0) red[wave] = lsum;
    __syncthreads();
    float segSum = red[0] + red[1] + red[2] + red[3];

    int p = pg * 256 + tid;
    float thisSum = 0.f;
    if (p < PTOT) {
        float c = pos[p] - THRESH;
        float aabs = 0.f;
        const float4* l4 = (const float4*)lneg;    // uniform addr -> broadcast
#pragma unroll 4
        for (int k = 0; k < SEG / 4; k++) {
            float4 n = l4[k];
            aabs += fabsf(n.x - c) + fabsf(n.y - c) +
                    fabsf(n.z - c) + fabsf(n.w - c);
        }
        thisSum = 0.5f * (segSum - (float)SEG * c + aabs);
    }
    for (int off = 32; off; off >>= 1) thisSum += __shfl_down(thisSum, off);
    __syncthreads();                                // red[] reuse
    if (lane == 0) red[wave] = thisSum;
    __syncthreads();

    if (tid == 0) {
        atomicAdd(acc, (double)(red[0] + red[1] + red[2] + red[3]));
        __threadfence();                            // release my acc add
        unsigned int prev = atomicAdd(counter, 1u);
        if (prev == NBLK2 - 1) {                    // I'm the last block
            __threadfence();                        // acquire others' adds
            double total = atomicAdd(acc, 0.0);     // coherent read
            out[0] = (float)(total /
                     (double)((long long)PTOT * (long long)QTOT));
        }
    }
}

extern "C" void kernel_launch(void* const* d_in, const int* in_sizes, int n_in,
                              void* d_out, int out_size, void* d_ws, size_t ws_size,
                              hipStream_t stream)
{
    const float* stereos  = (const float*)d_in[0];
    const float* astereos = (const float*)d_in[1];

    float*        pos     = (float*)d_ws;
    float*        neg     = pos + PTOT;
    double*       acc     = (double*)((char*)d_ws + (size_t)(PTOT + QTOT) * 4);
    unsigned int* counter = (unsigned int*)((char*)d_ws + (size_t)(PTOT + QTOT) * 4 + 8);
    float*        out     = (float*)d_out;

    sims_kernel<<<NBLK1, 256, 0, stream>>>(stereos, astereos, pos, neg, acc, counter);
    hinge_kernel<<<NBLK2, 256, 0, stream>>>(pos, neg, acc, counter, out);
}

// Round 4
// 79.266 us; speedup vs baseline: 2.5139x; 1.0731x over previous
//
#include <hip/hip_runtime.h>
#include <math.h>

#define NROWS   96
#define DIM     768
#define THRESH  0.3f
#define NPAIR   4560            // 96*95/2
#define PTOT    9120            // 2*NPAIR
#define QTOT    9216            // 96*96
#define NSEG    16
#define SEG     576             // QTOT / NSEG
#define NBLK    576
#define NWAVES  (NBLK * 4)      // 2304 waves; strips per quadrant = 96*24 = 2304
#define SPR     24              // 4-col strips per 96-col row

// ws layout (floats): posS[4560] | posA[4560] | negC[9216] | invn[192]
//   = 18528 floats = 74112 B, then acc (double) @74112, counter (u32) @74120

// 4-dot strip: row a . rows (b0..b3), returns per-lane partials in s0..s3
__device__ __forceinline__ void strip_dots(
    const float* __restrict__ rowa, const float* __restrict__ base_b,
    int j0, int lane, float& s0, float& s1, float& s2, float& s3)
{
    const float4* ra = (const float4*)rowa;
    float4 a0 = ra[lane], a1 = ra[lane + 64], a2 = ra[lane + 128];
    const float4* rb0 = (const float4*)(base_b + (j0 + 0) * DIM);
    const float4* rb1 = (const float4*)(base_b + (j0 + 1) * DIM);
    const float4* rb2 = (const float4*)(base_b + (j0 + 2) * DIM);
    const float4* rb3 = (const float4*)(base_b + (j0 + 3) * DIM);
#define DOT3(rb, s)                                                         \
    {                                                                       \
        float4 b0 = rb[lane], b1 = rb[lane + 64], b2 = rb[lane + 128];      \
        s = a0.x*b0.x + a0.y*b0.y + a0.z*b0.z + a0.w*b0.w                   \
          + a1.x*b1.x + a1.y*b1.y + a1.z*b1.z + a1.w*b1.w                   \
          + a2.x*b2.x + a2.y*b2.y + a2.z*b2.z + a2.w*b2.w;                  \
    }
    DOT3(rb0, s0) DOT3(rb1, s1) DOT3(rb2, s2) DOT3(rb3, s3)
#undef DOT3
    for (int off = 32; off; off >>= 1) {
        s0 += __shfl_down(s0, off);
        s1 += __shfl_down(s1, off);
        s2 += __shfl_down(s2, off);
        s3 += __shfl_down(s3, off);
    }
}

// ---- K1: raw gram strips + row inv-norms (independent; published at kernel
//          boundary). Also zeroes acc/counter. -------------------------------
__global__ __launch_bounds__(256) void gram_kernel(
    const float* __restrict__ stereos, const float* __restrict__ astereos,
    float* __restrict__ posS, float* __restrict__ posA,
    float* __restrict__ negC, float* __restrict__ invn,
    double* __restrict__ acc, unsigned int* __restrict__ counter)
{
    __shared__ float red[4];
    int tid  = threadIdx.x;
    int wave = tid >> 6, lane = tid & 63;

    if (blockIdx.x == 0 && tid == 0) { *acc = 0.0; *counter = 0u; }

    // norms: blocks 0..191, one row each (concurrent with strip work below)
    if (blockIdx.x < 2 * NROWS) {
        int row = blockIdx.x;
        const float* src = (row < NROWS) ? stereos + row * DIM
                                         : astereos + (row - NROWS) * DIM;
        float v0 = src[tid], v1 = src[tid + 256], v2 = src[tid + 512];
        float ss = v0 * v0 + v1 * v1 + v2 * v2;
        for (int off = 32; off; off >>= 1) ss += __shfl_down(ss, off);
        if (lane == 0) red[wave] = ss;
        __syncthreads();
        if (tid == 0) {
            float tot = red[0] + red[1] + red[2] + red[3];
            invn[row] = 1.0f / fmaxf(sqrtf(tot), 1e-8f);
        }
    }

    int gw = blockIdx.x * 4 + wave;                // 0..2303
    float s0, s1, s2, s3;

    // quadrant S: triu of stereos gram (store only j > i)
    {
        int i  = gw / SPR;
        int j0 = (gw - i * SPR) * 4;
        if (j0 + 3 > i) {
            strip_dots(stereos + i * DIM, stereos, j0, lane, s0, s1, s2, s3);
            if (lane == 0) {
                int base = (i * (191 - i)) / 2 - i - 1;   // tri idx = base + j
                float s[4] = {s0, s1, s2, s3};
#pragma unroll
                for (int m = 0; m < 4; m++)
                    if (j0 + m > i) posS[base + j0 + m] = s[m];
            }
        }
    }
    // quadrant A: triu of astereos gram, reversed strip id for load balance
    {
        int sw = NWAVES - 1 - gw;
        int i  = sw / SPR;
        int j0 = (sw - i * SPR) * 4;
        if (j0 + 3 > i) {
            strip_dots(astereos + i * DIM, astereos, j0, lane, s0, s1, s2, s3);
            if (lane == 0) {
                int base = (i * (191 - i)) / 2 - i - 1;
                float s[4] = {s0, s1, s2, s3};
#pragma unroll
                for (int m = 0; m < 4; m++)
                    if (j0 + m > i) posA[base + j0 + m] = s[m];
            }
        }
    }
    // quadrant C: full cross astereos x stereos
    {
        int qa = gw / SPR;
        int j0 = (gw - qa * SPR) * 4;
        strip_dots(astereos + qa * DIM, stereos, j0, lane, s0, s1, s2, s3);
        if (lane == 0) {
            float* o = negC + qa * 96 + j0;
            o[0] = s0; o[1] = s1; o[2] = s2; o[3] = s3;
        }
    }
}

// ---- K2: scale on load + hinge via abs identity + last-block finalize ------
// sum_q max(0, n_q - c) = 0.5*(segSum - SEG*c + sum_q |n_q - c|), c = p - T
__global__ __launch_bounds__(256) void hinge_kernel(
    const float* __restrict__ posS, const float* __restrict__ posA,
    const float* __restrict__ negC, const float* __restrict__ invn,
    double* __restrict__ acc, unsigned int* __restrict__ counter,
    float* __restrict__ out)
{
    __shared__ __align__(16) float lneg[SEG];
    __shared__ float red[4];
    int tid  = threadIdx.x;
    int wave = tid >> 6, lane = tid & 63;
    const float* invA = invn + NROWS;

    int seg = blockIdx.x & (NSEG - 1);
    int pg  = blockIdx.x >> 4;                     // 0..35

    // stage + scale this neg segment
    int qbase = seg * SEG;
    float lsum = 0.f;
    for (int k = tid; k < SEG; k += 256) {
        int q  = qbase + k;
        int qa = q / 96, qs = q - qa * 96;
        float v = negC[q] * invA[qa] * invn[qs];
        lneg[k] = v;
        lsum += v;
    }
    for (int off = 32; off; off >>= 1) lsum += __shfl_down(lsum, off);
    if (lane == 0) red[wave] = lsum;
    __syncthreads();
    float segSum = red[0] + red[1] + red[2] + red[3];

    int p = pg * 256 + tid;
    float thisSum = 0.f;
    if (p < PTOT) {
        int t = p;
        const float* praw = posS;
        const float* ib   = invn;
        if (p >= NPAIR) { t = p - NPAIR; praw = posA; ib = invA; }
        // decode once per thread: B(i) = i*(191-i)/2 <= t < B(i+1)
        int i = (int)((191.0 - sqrt(36481.0 - 8.0 * (double)t)) * 0.5);
        if (i < 0) i = 0;
        if (i > 94) i = 94;
        while (i > 0 && (i * (191 - i)) / 2 > t) --i;
        while (((i + 1) * (190 - i)) / 2 <= t) ++i;
        int j = t - (i * (191 - i)) / 2 + i + 1;
        float c = praw[t] * ib[i] * ib[j] - THRESH;

        float aabs = 0.f;
        const float4* l4 = (const float4*)lneg;    // uniform addr -> broadcast
#pragma unroll 4
        for (int k = 0; k < SEG / 4; k++) {
            float4 n = l4[k];
            aabs += fabsf(n.x - c) + fabsf(n.y - c) +
                    fabsf(n.z - c) + fabsf(n.w - c);
        }
        thisSum = 0.5f * (segSum - (float)SEG * c + aabs);
    }
    for (int off = 32; off; off >>= 1) thisSum += __shfl_down(thisSum, off);
    __syncthreads();                                // red[] reuse
    if (lane == 0) red[wave] = thisSum;
    __syncthreads();

    if (tid == 0) {
        atomicAdd(acc, (double)(red[0] + red[1] + red[2] + red[3]));
        __threadfence();                            // release my acc add
        unsigned int prev = atomicAdd(counter, 1u);
        if (prev == NBLK - 1) {                     // last block finalizes
            __threadfence();                        // acquire others' adds
            double total = atomicAdd(acc, 0.0);     // coherent read
            out[0] = (float)(total /
                     (double)((long long)PTOT * (long long)QTOT));
        }
    }
}

extern "C" void kernel_launch(void* const* d_in, const int* in_sizes, int n_in,
                              void* d_out, int out_size, void* d_ws, size_t ws_size,
                              hipStream_t stream)
{
    const float* stereos  = (const float*)d_in[0];
    const float* astereos = (const float*)d_in[1];

    float*        posS    = (float*)d_ws;
    float*        posA    = posS + NPAIR;
    float*        negC    = posA + NPAIR;
    float*        invn    = negC + QTOT;
    double*       acc     = (double*)((char*)d_ws + 74112);
    unsigned int* counter = (unsigned int*)((char*)d_ws + 74120);
    float*        out     = (float*)d_out;

    gram_kernel<<<NBLK, 256, 0, stream>>>(stereos, astereos, posS, posA,
                                          negC, invn, acc, counter);
    hinge_kernel<<<NBLK, 256, 0, stream>>>(posS, posA, negC, invn,
                                           acc, counter, out);
}

// Round 5
// 67.233 us; speedup vs baseline: 2.9638x; 1.1790x over previous
//
#include <hip/hip_runtime.h>
#include <math.h>

#define NROWS   96
#define DIM     768
#define THRESH  0.3f
#define NPAIR   4560            // 96*95/2
#define PTOT    9120            // 2*NPAIR
#define QTOT    9216            // 96*96
#define NDOT    18336           // PTOT + QTOT
#define NBLK1   576
#define NWAVES  (NBLK1 * 4)     // 2304 waves; strips per quadrant = 96*24
#define SPR     24              // 4-col strips per 96-col row
#define NBLK2   72              // 72*256 = 18432 >= NDOT

// ws layout (bytes):
//   pos[9120] f32 @0          (posS @0, posA @4560 floats; raw then scaled)
//   neg[9216] f32 @36480
//   invn[192] f32 @73344
//   Sp f64 @74112 | Sn f64 @74120 | counter u32 @74128 |
//   pmax_key u32 @74132 | nmin_key u32 @74136

// order-preserving float<->uint key (monotone map for atomicMax/Min)
__device__ __forceinline__ unsigned fkey(float x) {
    int ix = __float_as_int(x);
    return (ix >= 0) ? ((unsigned)ix | 0x80000000u) : (unsigned)(~ix);
}
__device__ __forceinline__ float funkey(unsigned k) {
    int ix = (k & 0x80000000u) ? (int)(k & 0x7fffffffu) : ~(int)k;
    return __int_as_float(ix);
}

// 4-dot strip: row a . rows (b0..b3), per-lane partials reduced across wave
__device__ __forceinline__ void strip_dots(
    const float* __restrict__ rowa, const float* __restrict__ base_b,
    int j0, int lane, float& s0, float& s1, float& s2, float& s3)
{
    const float4* ra = (const float4*)rowa;
    float4 a0 = ra[lane], a1 = ra[lane + 64], a2 = ra[lane + 128];
    const float4* rb0 = (const float4*)(base_b + (j0 + 0) * DIM);
    const float4* rb1 = (const float4*)(base_b + (j0 + 1) * DIM);
    const float4* rb2 = (const float4*)(base_b + (j0 + 2) * DIM);
    const float4* rb3 = (const float4*)(base_b + (j0 + 3) * DIM);
#define DOT3(rb, s)                                                         \
    {                                                                       \
        float4 b0 = rb[lane], b1 = rb[lane + 64], b2 = rb[lane + 128];      \
        s = a0.x*b0.x + a0.y*b0.y + a0.z*b0.z + a0.w*b0.w                   \
          + a1.x*b1.x + a1.y*b1.y + a1.z*b1.z + a1.w*b1.w                   \
          + a2.x*b2.x + a2.y*b2.y + a2.z*b2.z + a2.w*b2.w;                  \
    }
    DOT3(rb0, s0) DOT3(rb1, s1) DOT3(rb2, s2) DOT3(rb3, s3)
#undef DOT3
    for (int off = 32; off; off >>= 1) {
        s0 += __shfl_down(s0, off);
        s1 += __shfl_down(s1, off);
        s2 += __shfl_down(s2, off);
        s3 += __shfl_down(s3, off);
    }
}

// ---- K1: raw gram strips + row inv-norms; init K2 scalars ------------------
__global__ __launch_bounds__(256) void gram_kernel(
    const float* __restrict__ stereos, const float* __restrict__ astereos,
    float* __restrict__ pos, float* __restrict__ neg,
    float* __restrict__ invn, double* __restrict__ Sp, double* __restrict__ Sn,
    unsigned* __restrict__ counter, unsigned* __restrict__ pmax_key,
    unsigned* __restrict__ nmin_key)
{
    __shared__ float red[4];
    int tid  = threadIdx.x;
    int wave = tid >> 6, lane = tid & 63;

    if (blockIdx.x == 0 && tid == 0) {
        *Sp = 0.0; *Sn = 0.0; *counter = 0u;
        *pmax_key = 0u;              // maps below all reals
        *nmin_key = 0xFFFFFFFFu;     // maps above all reals
    }

    // norms: blocks 0..191, one row each (concurrent with strip work)
    if (blockIdx.x < 2 * NROWS) {
        int row = blockIdx.x;
        const float* src = (row < NROWS) ? stereos + row * DIM
                                         : astereos + (row - NROWS) * DIM;
        float v0 = src[tid], v1 = src[tid + 256], v2 = src[tid + 512];
        float ss = v0 * v0 + v1 * v1 + v2 * v2;
        for (int off = 32; off; off >>= 1) ss += __shfl_down(ss, off);
        if (lane == 0) red[wave] = ss;
        __syncthreads();
        if (tid == 0) {
            float tot = red[0] + red[1] + red[2] + red[3];
            invn[row] = 1.0f / fmaxf(sqrtf(tot), 1e-8f);
        }
    }

    int gw = blockIdx.x * 4 + wave;                // 0..2303
    float s0, s1, s2, s3;

    // quadrant S: triu of stereos gram (store only j > i)
    {
        int i  = gw / SPR;
        int j0 = (gw - i * SPR) * 4;
        if (j0 + 3 > i) {
            strip_dots(stereos + i * DIM, stereos, j0, lane, s0, s1, s2, s3);
            if (lane == 0) {
                int base = (i * (191 - i)) / 2 - i - 1;   // tri idx = base + j
                float s[4] = {s0, s1, s2, s3};
#pragma unroll
                for (int m = 0; m < 4; m++)
                    if (j0 + m > i) pos[base + j0 + m] = s[m];
            }
        }
    }
    // quadrant A: triu of astereos gram, reversed strip id for load balance
    {
        int sw = NWAVES - 1 - gw;
        int i  = sw / SPR;
        int j0 = (sw - i * SPR) * 4;
        if (j0 + 3 > i) {
            strip_dots(astereos + i * DIM, astereos, j0, lane, s0, s1, s2, s3);
            if (lane == 0) {
                int base = (i * (191 - i)) / 2 - i - 1;
                float s[4] = {s0, s1, s2, s3};
#pragma unroll
                for (int m = 0; m < 4; m++)
                    if (j0 + m > i) pos[NPAIR + base + j0 + m] = s[m];
            }
        }
    }
    // quadrant C: full cross astereos x stereos
    {
        int qa = gw / SPR;
        int j0 = (gw - qa * SPR) * 4;
        strip_dots(astereos + qa * DIM, stereos, j0, lane, s0, s1, s2, s3);
        if (lane == 0) {
            float* o = neg + qa * 96 + j0;
            o[0] = s0; o[1] = s1; o[2] = s2; o[3] = s3;
        }
    }
}

// ---- K2: scale in place + analytic hinge + exact rare-path correction ------
// sum max(0, n-p+T) = P*Sn - Q*Sp + P*Q*T + sum relu(p - T - n)
// (last term exactly 0 unless pmax - nmin > T)
__global__ __launch_bounds__(256) void reduce_kernel(
    float* __restrict__ pos, float* __restrict__ neg,
    const float* __restrict__ invn, double* __restrict__ Sp,
    double* __restrict__ Sn, unsigned* __restrict__ counter,
    unsigned* __restrict__ pmax_key, unsigned* __restrict__ nmin_key,
    float* __restrict__ out)
{
    __shared__ float  redp[4], redn[4], redmx[4], redmn[4];
    __shared__ int    isLast;
    __shared__ double bcast[2];
    __shared__ float  bcastf[2];
    __shared__ double redd[4];

    int tid  = threadIdx.x;
    int wave = tid >> 6, lane = tid & 63;
    int g = blockIdx.x * 256 + tid;

    float vp = 0.f, vn = 0.f;
    float mp = -INFINITY, mn = INFINITY;

    if (g < PTOT) {
        int t = (g < NPAIR) ? g : g - NPAIR;
        const float* ib = (g < NPAIR) ? invn : invn + NROWS;
        // triangular decode: B(i) = i*(191-i)/2 <= t < B(i+1)
        int i = (int)((191.0 - sqrt(36481.0 - 8.0 * (double)t)) * 0.5);
        if (i < 0) i = 0;
        if (i > 94) i = 94;
        while (i > 0 && (i * (191 - i)) / 2 > t) --i;
        while (((i + 1) * (190 - i)) / 2 <= t) ++i;
        int j = t - (i * (191 - i)) / 2 + i + 1;
        float v = pos[g] * ib[i] * ib[j];
        pos[g] = v;                                // scaled, for rare path
        vp = v; mp = v;
    } else if (g < NDOT) {
        int q  = g - PTOT;
        int qa = q / NROWS, qs = q - qa * NROWS;
        float v = neg[q] * invn[NROWS + qa] * invn[qs];
        neg[q] = v;
        vn = v; mn = v;
    }

    for (int off = 32; off; off >>= 1) {
        vp += __shfl_down(vp, off);
        vn += __shfl_down(vn, off);
        mp = fmaxf(mp, __shfl_down(mp, off));
        mn = fminf(mn, __shfl_down(mn, off));
    }
    if (lane == 0) { redp[wave] = vp; redn[wave] = vn;
                     redmx[wave] = mp; redmn[wave] = mn; }
    __syncthreads();
    if (tid == 0) {
        float bsp = redp[0] + redp[1] + redp[2] + redp[3];
        float bsn = redn[0] + redn[1] + redn[2] + redn[3];
        float bmx = fmaxf(fmaxf(redmx[0], redmx[1]), fmaxf(redmx[2], redmx[3]));
        float bmn = fminf(fminf(redmn[0], redmn[1]), fminf(redmn[2], redmn[3]));
        atomicAdd(Sp, (double)bsp);
        atomicAdd(Sn, (double)bsn);
        atomicMax(pmax_key, fkey(bmx));
        atomicMin(nmin_key, fkey(bmn));
        __threadfence();                            // release scaled stores+adds
        unsigned prev = atomicAdd(counter, 1u);
        isLast = (prev == NBLK2 - 1) ? 1 : 0;
    }
    __syncthreads();

    if (isLast) {
        __threadfence();                            // acquire
        if (tid == 0) {
            bcast[0]  = atomicAdd(Sp, 0.0);         // coherent reads
            bcast[1]  = atomicAdd(Sn, 0.0);
            bcastf[0] = funkey(atomicOr(pmax_key, 0u));
            bcastf[1] = funkey(atomicOr(nmin_key, 0u));
        }
        __syncthreads();
        double sp = bcast[0], sn = bcast[1];
        float pmax = bcastf[0], nmin = bcastf[1];

        double corr = 0.0;
        if (pmax - nmin > THRESH) {                 // exact rare-path fallback
            volatile const float* vposp = pos;
            volatile const float* vnegp = neg;
            for (int p = tid; p < PTOT; p += 256) {
                float pv = vposp[p];
                if (pv - nmin > THRESH) {
                    for (int q = 0; q < QTOT; q++) {
                        float d = pv - THRESH - vnegp[q];
                        if (d > 0.f) corr += (double)d;
                    }
                }
            }
        }
        for (int off = 32; off; off >>= 1) corr += __shfl_down(corr, off);
        if (lane == 0) redd[wave] = corr;
        __syncthreads();
        if (tid == 0) {
            corr = redd[0] + redd[1] + redd[2] + redd[3];
            double PQ = (double)PTOT * (double)QTOT;
            double total = (double)PTOT * sn - (double)QTOT * sp
                         + PQ * (double)THRESH + corr;
            out[0] = (float)(total / PQ);
        }
    }
}

extern "C" void kernel_launch(void* const* d_in, const int* in_sizes, int n_in,
                              void* d_out, int out_size, void* d_ws, size_t ws_size,
                              hipStream_t stream)
{
    const float* stereos  = (const float*)d_in[0];
    const float* astereos = (const float*)d_in[1];

    char* ws = (char*)d_ws;
    float*    pos      = (float*)ws;
    float*    neg      = (float*)(ws + 36480);
    float*    invn     = (float*)(ws + 73344);
    double*   Sp       = (double*)(ws + 74112);
    double*   Sn       = (double*)(ws + 74120);
    unsigned* counter  = (unsigned*)(ws + 74128);
    unsigned* pmax_key = (unsigned*)(ws + 74132);
    unsigned* nmin_key = (unsigned*)(ws + 74136);
    float*    out      = (float*)d_out;

    gram_kernel<<<NBLK1, 256, 0, stream>>>(stereos, astereos, pos, neg, invn,
                                           Sp, Sn, counter, pmax_key, nmin_key);
    reduce_kernel<<<NBLK2, 256, 0, stream>>>(pos, neg, invn, Sp, Sn, counter,
                                             pmax_key, nmin_key, out);
}